// Round 6
// baseline (128.683 us; speedup 1.0000x reference)
//
#include <hip/hip_runtime.h>
#include <hip/hip_bf16.h>

// out = x @ (Wc + Wn) + b   -- gamma/segment ops in the reference are dead code.
// x: [100000,128] f32, Wc/Wn: [128,128] f32, b: [128] f32, out: [100000,128] f32.
//
// R6: barrier-free gemm. R5's LDS staging forced a per-block s_waitcnt
// vmcnt(0) drain at __syncthreads (all x loads + staging loads complete
// before the first MFMA) -> fully phase-serialized blocks. Here W (32KB bf16,
// exactly L1-sized) is pre-packed in FRAGMENT-MAJOR order, so each wave's
// A-fragment load is one perfectly-coalesced 64x16B global load served from
// L1/L2. No LDS, no barrier; the compiler's fine-grained vmcnt lets MFMA
// overlap the in-flight loads. x uses nontemporal loads (streaming; don't
// evict wt from L1); out uses nontemporal stores (write-once).
//
// MFMA operands: A = W^T fragment, B = x fragment (identical input lane maps)
// -> D[m=out_col][n=x_row] gives 4 contiguous out columns/lane -> float4 stores.

#define NROWS 100000

typedef __attribute__((ext_vector_type(8))) __bf16 bf16x8;
typedef __attribute__((ext_vector_type(4))) float f32x4;

__device__ __forceinline__ bf16x8 pack8(const f32x4 lo, const f32x4 hi) {
    bf16x8 r;  // gfx950: v_cvt_pk_bf16_f32 (RNE)
    r[0] = (__bf16)lo[0]; r[1] = (__bf16)lo[1]; r[2] = (__bf16)lo[2]; r[3] = (__bf16)lo[3];
    r[4] = (__bf16)hi[0]; r[5] = (__bf16)hi[1]; r[6] = (__bf16)hi[2]; r[7] = (__bf16)hi[3];
    return r;
}

// Fragment-major packed W^T:  wtL[((ct*4+kc)*16 + l16)*32 + quad*8 + j]
//   = bf16( Wc[k][n] + Wn[k][n] ),  n = ct*16+l16,  k = kc*32+quad*8+j.
// Each (ct,kc) fragment occupies one contiguous 1KB block -> a wave's
// fragment load covers exactly [frag*1KB, frag*1KB+1KB) with 16B/lane.
// Thread t handles one (n, k-octet): reads coalesced over n, writes bf16x8.
__global__ void prep_wt(const float* __restrict__ Wc, const float* __restrict__ Wn,
                        __bf16* __restrict__ wtL) {
    int t = blockIdx.x * 256 + threadIdx.x;   // 2048 threads
    int n = t & 127;                          // consecutive lanes -> consecutive n (coalesced reads)
    int oct = t >> 7;                         // k-octet 0..15
    int ct = n >> 4, l16 = n & 15;
    int kc = oct >> 2, quad = oct & 3;
    bf16x8 v;
    #pragma unroll
    for (int j = 0; j < 8; ++j) {
        int k = (oct << 3) + j;
        v[j] = (__bf16)(Wc[k * 128 + n] + Wn[k * 128 + n]);
    }
    *(bf16x8*)&wtL[(((ct * 4 + kc) * 16 + l16) * 4 + quad) * 8] = v;
}

// 128 rows per block, 4 waves x 32 rows, full N=128 / K=128 per block.
__global__ __launch_bounds__(256, 3) void gemm_bias(
    const float* __restrict__ x, const __bf16* __restrict__ wtL,
    const float* __restrict__ bias_g, float* __restrict__ out) {

    const int tid  = threadIdx.x;
    const int wave = tid >> 6;
    const int lane = tid & 63;
    const int quad = lane >> 4;
    const int l16  = lane & 15;

    const long rowbase = (long)blockIdx.x * 128 + wave * 32;
    if (rowbase >= NROWS) return;   // 100000 % 32 == 0: whole-wave granularity, no barrier to honor

    // ---- x loads (nontemporal: streaming, keep wt L1-resident) ----
    // B[k = quad*8 + j][n = lane&15] -> rows (rowbase+l16) and (+16)
    bf16x8 xb[2][4];
    {
        const f32x4* xr0 = (const f32x4*)(x + (rowbase + l16) * 128);
        const f32x4* xr1 = (const f32x4*)(x + (rowbase + 16 + l16) * 128);
        #pragma unroll
        for (int kc = 0; kc < 4; ++kc) {
            const int q4 = kc * 8 + quad * 2;   // float4 index of k-octet start
            f32x4 lo0 = __builtin_nontemporal_load(xr0 + q4);
            f32x4 hi0 = __builtin_nontemporal_load(xr0 + q4 + 1);
            f32x4 lo1 = __builtin_nontemporal_load(xr1 + q4);
            f32x4 hi1 = __builtin_nontemporal_load(xr1 + q4 + 1);
            xb[0][kc] = pack8(lo0, hi0);
            xb[1][kc] = pack8(lo1, hi1);
        }
    }

    // bias for cols ct*16 + quad*4 .. +3 (L1-hot broadcast)
    f32x4 bv[8];
    #pragma unroll
    for (int ct = 0; ct < 8; ++ct)
        bv[ct] = *(const f32x4*)(bias_g + ct * 16 + quad * 4);

    // ---- MFMA loop: W fragments straight from L1-hot packed wt ----
    f32x4 acc[2][8] = {};   // 2 row-groups (16 rows) x 8 col-tiles
    const __bf16* wf = wtL + l16 * 32 + quad * 8;   // + (ct*4+kc)*512 per fragment
    #pragma unroll
    for (int kc = 0; kc < 4; ++kc) {
        #pragma unroll
        for (int ct = 0; ct < 8; ++ct) {
            bf16x8 wa = *(const bf16x8*)(wf + (ct * 4 + kc) * 512);
            acc[0][ct] = __builtin_amdgcn_mfma_f32_16x16x32_bf16(wa, xb[0][kc], acc[0][ct], 0, 0, 0);
            acc[1][ct] = __builtin_amdgcn_mfma_f32_16x16x32_bf16(wa, xb[1][kc], acc[1][ct], 0, 0, 0);
        }
    }

    // ---- epilogue: D[m=out_col][n=x_row]; cols quad*4+reg contiguous ----
    #pragma unroll
    for (int g = 0; g < 2; ++g) {
        float* orow = out + (rowbase + g * 16 + l16) * 128 + quad * 4;
        #pragma unroll
        for (int ct = 0; ct < 8; ++ct) {
            f32x4 v = acc[g][ct] + bv[ct];
            __builtin_nontemporal_store(v, (f32x4*)(orow + ct * 16));
        }
    }
}

extern "C" void kernel_launch(void* const* d_in, const int* in_sizes, int n_in,
                              void* d_out, int out_size, void* d_ws, size_t ws_size,
                              hipStream_t stream) {
    const float* x  = (const float*)d_in[0];
    // d_in[1] = edge_index (int64) -- dead code in the reference, never read.
    const float* Wc = (const float*)d_in[2];
    const float* Wn = (const float*)d_in[3];
    const float* b  = (const float*)d_in[4];
    __bf16* wtL = (__bf16*)d_ws;   // 32 KB scratch, fragment-major packed W^T
    float* out = (float*)d_out;

    prep_wt<<<8, 256, 0, stream>>>(Wc, Wn, wtL);
    const int nblocks = (NROWS + 127) / 128;      // 782
    gemm_bias<<<nblocks, 256, 0, stream>>>(x, wtL, b, out);
}

// Round 7
// 118.225 us; speedup vs baseline: 1.0885x; 1.0885x over previous
//
#include <hip/hip_runtime.h>
#include <hip/hip_bf16.h>

// out = x @ (Wc + Wn) + b   -- gamma/segment ops in the reference are dead code.
// x: [100000,128] f32, Wc/Wn: [128,128] f32, b: [128] f32, out: [100000,128] f32.
//
// R7 = best-of-all-rounds combination:
//   * prep_wt pre-transposes W^T in bf16 (R5: in-block transpose = 32-way
//     ds_write bank conflicts, 6.4M conflict cycles -- R4 post-mortem).
//   * gemm stages wt via contiguous b128 reads -> b128 LDS writes (conflict-free).
//   * x loads AFTER __syncthreads (R1's placement): the barrier's vmcnt(0)
//     drains only the 8 L2-hot wt staging loads, not 64KB of HBM x traffic.
//     The unrolled k-loop lets the compiler hoist x loads with fine-grained
//     vmcnt(N), overlapping MFMA/LDS with in-flight x. (R5 hoisted x BEFORE
//     the barrier -> full phase serialization; R6 dropped LDS entirely ->
//     per-wave L2 re-reads of wt stalled MFMA. Both regressed.)
//   * MFMA operands: A = W^T fragment, B = x fragment (identical input lane
//     maps) -> D[m=out_col][n=x_row]: 4 contiguous out cols/lane -> float4
//     nontemporal stores (write-once stream).

#define NROWS 100000

typedef __attribute__((ext_vector_type(8))) __bf16 bf16x8;
typedef __attribute__((ext_vector_type(4))) float f32x4;

__device__ __forceinline__ bf16x8 pack8(const f32x4 lo, const f32x4 hi) {
    bf16x8 r;  // gfx950: v_cvt_pk_bf16_f32 (RNE)
    r[0] = (__bf16)lo[0]; r[1] = (__bf16)lo[1]; r[2] = (__bf16)lo[2]; r[3] = (__bf16)lo[3];
    r[4] = (__bf16)hi[0]; r[5] = (__bf16)hi[1]; r[6] = (__bf16)hi[2]; r[7] = (__bf16)hi[3];
    return r;
}

// Build Wt[n][k] = bf16(Wc[k][n] + Wn[k][n]) in workspace. Consecutive threads
// share k, vary n -> global reads coalesced; linear bf16 writes.
__global__ void prep_wt(const float* __restrict__ Wc, const float* __restrict__ Wn,
                        __bf16* __restrict__ wt) {
    int i = blockIdx.x * 256 + threadIdx.x;   // wt laid out [n][k], i = n*128+k
    int n = i >> 7, k = i & 127;
    wt[i] = (__bf16)(Wc[k * 128 + n] + Wn[k * 128 + n]);
}

// 128 rows per block, 4 waves x 32 rows, full N=128 / K=128 per block.
__global__ __launch_bounds__(256) void gemm_bias(
    const float* __restrict__ x, const __bf16* __restrict__ wt,
    const float* __restrict__ bias_g, float* __restrict__ out) {

    // 136-short row stride: rows 16B-aligned (272B); fragment reads are 2-way
    // bank-aliased at worst (free, m136).
    __shared__ __align__(16) __bf16 sWt[128 * 136];

    const int tid  = threadIdx.x;
    const int wave = tid >> 6;
    const int lane = tid & 63;
    const int quad = lane >> 4;
    const int l16  = lane & 15;

    // ---- W staging first: contiguous b128 reads of pre-transposed wt ->
    // b128 LDS writes; lanes 0..15 cover one 272B row contiguously.
    // Only these 8 loads are outstanding at the barrier.
    #pragma unroll
    for (int it = 0; it < 8; ++it) {
        int idx8 = it * 256 + tid;           // 16B chunk id, 16 chunks per row
        int n = idx8 >> 4;
        int k = (idx8 & 15) << 3;
        *(bf16x8*)&sWt[n * 136 + k] = *(const bf16x8*)(wt + (idx8 << 3));
    }
    __syncthreads();

    const long rowbase = (long)blockIdx.x * 128 + wave * 32;
    if (rowbase >= NROWS) return;   // 100000 % 32 == 0: whole-wave granularity

    // bias for cols ct*16 + quad*4 .. +3 (L1-hot broadcast)
    f32x4 bv[8];
    #pragma unroll
    for (int ct = 0; ct < 8; ++ct)
        bv[ct] = *(const f32x4*)(bias_g + ct * 16 + quad * 4);

    // ---- main loop: x loads (post-barrier, fine-grained vmcnt) + MFMA ----
    // B[k = quad*8 + j][n = lane&15] -> rows (rowbase+l16) and (+16)
    const f32x4* xr0 = (const f32x4*)(x + (rowbase + l16) * 128);
    const f32x4* xr1 = (const f32x4*)(x + (rowbase + 16 + l16) * 128);

    f32x4 acc[2][8] = {};   // 2 row-groups (16 rows) x 8 col-tiles
    #pragma unroll
    for (int kc = 0; kc < 4; ++kc) {
        const int q4 = kc * 8 + quad * 2;   // float4 index of k-octet start
        bf16x8 xb0 = pack8(xr0[q4], xr0[q4 + 1]);
        bf16x8 xb1 = pack8(xr1[q4], xr1[q4 + 1]);
        const int ko = kc * 32 + quad * 8;
        #pragma unroll
        for (int ct = 0; ct < 8; ++ct) {
            // A-fragment: A[m = out_col = ct*16 + l16][k]
            bf16x8 wa = *(const bf16x8*)&sWt[(ct * 16 + l16) * 136 + ko];
            acc[0][ct] = __builtin_amdgcn_mfma_f32_16x16x32_bf16(wa, xb0, acc[0][ct], 0, 0, 0);
            acc[1][ct] = __builtin_amdgcn_mfma_f32_16x16x32_bf16(wa, xb1, acc[1][ct], 0, 0, 0);
        }
    }

    // ---- epilogue: D[m=out_col][n=x_row]; cols quad*4+reg contiguous ----
    #pragma unroll
    for (int g = 0; g < 2; ++g) {
        float* orow = out + (rowbase + g * 16 + l16) * 128 + quad * 4;
        #pragma unroll
        for (int ct = 0; ct < 8; ++ct) {
            f32x4 v = acc[g][ct] + bv[ct];
            __builtin_nontemporal_store(v, (f32x4*)(orow + ct * 16));
        }
    }
}

extern "C" void kernel_launch(void* const* d_in, const int* in_sizes, int n_in,
                              void* d_out, int out_size, void* d_ws, size_t ws_size,
                              hipStream_t stream) {
    const float* x  = (const float*)d_in[0];
    // d_in[1] = edge_index (int64) -- dead code in the reference, never read.
    const float* Wc = (const float*)d_in[2];
    const float* Wn = (const float*)d_in[3];
    const float* b  = (const float*)d_in[4];
    __bf16* wt = (__bf16*)d_ws;   // 32 KB scratch
    float* out = (float*)d_out;

    prep_wt<<<64, 256, 0, stream>>>(Wc, Wn, wt);
    const int nblocks = (NROWS + 127) / 128;      // 782
    gemm_bias<<<nblocks, 256, 0, stream>>>(x, wt, b, out);
}